// Round 3
// baseline (198.393 us; speedup 1.0000x reference)
//
#include <hip/hip_runtime.h>
#include <hip/hip_bf16.h>
#include <stdint.h>

#define BB 4
#define SS 4096
#define EE 1024
#define DD 64

typedef __attribute__((ext_vector_type(8))) short short8;
typedef __attribute__((ext_vector_type(4))) float f32x4;

__device__ inline uint32_t cvtpk(float lo, float hi) {
    uint32_t r;
    asm("v_cvt_pk_bf16_f32 %0, %1, %2" : "=v"(r) : "v"(lo), "v"(hi));
    return r;
}
__device__ inline float bf2f_lo(uint32_t u) {
    union { uint32_t u; float f; } v; v.u = u << 16; return v.f;
}
__device__ inline float bf2f_hi(uint32_t u) {
    union { uint32_t u; float f; } v; v.u = u & 0xFFFF0000u; return v.f;
}

#define SWZ16(r, bc) ((bc) ^ (((r) & 7) << 4))

// ---------- W f32 -> bf16 concat [192][1024] ----------
__global__ __launch_bounds__(256) void wconv_kernel(
    const float* __restrict__ Wq, const float* __restrict__ Wk,
    const float* __restrict__ Wv, ushort* __restrict__ Wb)
{
    int tid = blockIdx.x * 256 + threadIdx.x;
    int sel = tid >> 13;
    int off = (tid & 8191) * 8;
    const float* src = (sel == 0) ? Wq : ((sel == 1) ? Wk : Wv);
    float4 a = *reinterpret_cast<const float4*>(src + off);
    float4 b = *reinterpret_cast<const float4*>(src + off + 4);
    uint4 o;
    o.x = cvtpk(a.x, a.y); o.y = cvtpk(a.z, a.w);
    o.z = cvtpk(b.x, b.y); o.w = cvtpk(b.z, b.w);
    *reinterpret_cast<uint4*>(Wb + (size_t)sel * 65536 + off) = o;
}

// ---------- Projection (reg-prefetch pipelined) ----------
__global__ __launch_bounds__(256) void proj_kernel(
    const float* __restrict__ x, const ushort* __restrict__ Wb,
    ushort* __restrict__ q_ws, ushort* __restrict__ k_ws, ushort* __restrict__ vT_ws)
{
    __shared__ __align__(16) ushort x_lds[64 * 64];
    __shared__ __align__(16) ushort w_lds[192 * 64];
    const int t = threadIdx.x;
    const int wid = t >> 6, lane = t & 63, g = lane >> 4, lr = lane & 15;
    const int m0 = blockIdx.x * 64;

    f32x4 acc[3][4];
#pragma unroll
    for (int ni = 0; ni < 3; ++ni)
#pragma unroll
        for (int mi = 0; mi < 4; ++mi) acc[ni][mi] = (f32x4)(0.0f);

    float4 xr[4];
    uint4 wr[6];
    const int xrow = t >> 4, xc4 = t & 15;          // x: row 0..63 (t/16? no: 256 thr -> 4 iters)
    // per-thread fixed coords for staging
    // x: idx = i*256+t -> row=idx>>4, c4=idx&15
    // w: idx = i*256+t -> row=idx>>3, c8=idx&7

#define LOADX(E0) do { \
    _Pragma("unroll") \
    for (int i = 0; i < 4; ++i) { \
        int idx = i * 256 + t; int row = idx >> 4, c4 = idx & 15; \
        xr[i] = *reinterpret_cast<const float4*>(&x[(size_t)(m0 + row) * EE + (E0) + c4 * 4]); \
    } \
} while (0)
#define LOADW(E0) do { \
    _Pragma("unroll") \
    for (int i = 0; i < 6; ++i) { \
        int idx = i * 256 + t; int row = idx >> 3, c8 = idx & 7; \
        wr[i] = *reinterpret_cast<const uint4*>(&Wb[(size_t)row * EE + (E0) + c8 * 8]); \
    } \
} while (0)

    LOADX(0); LOADW(0);
    for (int e0 = 0; e0 < EE; e0 += 64) {
        // write staged regs to LDS
#pragma unroll
        for (int i = 0; i < 4; ++i) {
            int idx = i * 256 + t; int row = idx >> 4, c4 = idx & 15;
            uint2 p; p.x = cvtpk(xr[i].x, xr[i].y); p.y = cvtpk(xr[i].z, xr[i].w);
            *reinterpret_cast<uint2*>((char*)x_lds + row * 128 + SWZ16(row, c4 * 8)) = p;
        }
#pragma unroll
        for (int i = 0; i < 6; ++i) {
            int idx = i * 256 + t; int row = idx >> 3, c8 = idx & 7;
            *reinterpret_cast<uint4*>((char*)w_lds + row * 128 + SWZ16(row, c8 * 16)) = wr[i];
        }
        __syncthreads();
        if (e0 + 64 < EE) { LOADX(e0 + 64); LOADW(e0 + 64); }

        short8 af[3][2], bf[4][2];
#pragma unroll
        for (int ni = 0; ni < 3; ++ni)
#pragma unroll
            for (int c = 0; c < 2; ++c) {
                int row = wid * 48 + ni * 16 + lr;
                af[ni][c] = *reinterpret_cast<const short8*>((const char*)w_lds + row * 128 + SWZ16(row, c * 64 + g * 16));
            }
#pragma unroll
        for (int mi = 0; mi < 4; ++mi)
#pragma unroll
            for (int c = 0; c < 2; ++c) {
                int row = mi * 16 + lr;
                bf[mi][c] = *reinterpret_cast<const short8*>((const char*)x_lds + row * 128 + SWZ16(row, c * 64 + g * 16));
            }
#pragma unroll
        for (int ni = 0; ni < 3; ++ni)
#pragma unroll
            for (int mi = 0; mi < 4; ++mi)
#pragma unroll
                for (int c = 0; c < 2; ++c)
                    acc[ni][mi] = __builtin_amdgcn_mfma_f32_16x16x32_bf16(af[ni][c], bf[mi][c], acc[ni][mi], 0, 0, 0);
        __syncthreads();
    }

#pragma unroll
    for (int ni = 0; ni < 3; ++ni) {
        int n0 = wid * 48 + ni * 16 + 4 * g;
        int sel = n0 >> 6, d0 = n0 & 63;
#pragma unroll
        for (int mi = 0; mi < 4; ++mi) {
            int m = m0 + mi * 16 + lr;
            int b = m >> 12, s = m & (SS - 1);
            uint2 p;
            p.x = cvtpk(acc[ni][mi][0], acc[ni][mi][1]);
            p.y = cvtpk(acc[ni][mi][2], acc[ni][mi][3]);
            if (sel == 0) {
                *reinterpret_cast<uint2*>(q_ws + ((size_t)b * SS + s) * DD + d0) = p;
            } else if (sel == 1) {
                *reinterpret_cast<uint2*>(k_ws + ((size_t)b * SS + s) * DD + d0) = p;
            } else {
                vT_ws[((size_t)b * DD + d0 + 0) * SS + s] = (ushort)(p.x & 0xFFFF);
                vT_ws[((size_t)b * DD + d0 + 1) * SS + s] = (ushort)(p.x >> 16);
                vT_ws[((size_t)b * DD + d0 + 2) * SS + s] = (ushort)(p.y & 0xFFFF);
                vT_ws[((size_t)b * DD + d0 + 3) * SS + s] = (ushort)(p.y >> 16);
            }
        }
    }
}

// ---------- Flash attention, split-KV: 1 wave per (q-tile, kv-fragment) ----------
__global__ __launch_bounds__(64, 4) void attn_kernel(
    const ushort* __restrict__ q_ws, const ushort* __restrict__ k_ws,
    const ushort* __restrict__ vT_ws, uint32_t* __restrict__ pO32,
    float* __restrict__ pml)
{
    __shared__ __align__(16) ushort P_lds[16 * 72];
    const int lane = threadIdx.x, g = lane >> 4, lr = lane & 15;
    const int bid = blockIdx.x;
    const int f = bid & 3;
    const int b = (bid >> 2) & 3;
    const int qt = 255 - (bid >> 4);      // heavy q-tiles first
    const int qb = qt * 16;

    const ushort* qp = q_ws + ((size_t)b * SS + qb + lr) * DD;
    short8 qf0 = *reinterpret_cast<const short8*>(qp + g * 8);
    short8 qf1 = *reinterpret_cast<const short8*>(qp + 32 + g * 8);

    float m_r = -1e30f, l_r = 0.0f;
    f32x4 acc[4];
#pragma unroll
    for (int i = 0; i < 4; ++i) acc[i] = (f32x4)(0.0f);

    const float sc = 0.125f * 1.44269504f;
    const int nt = (qb + 79) >> 6;        // total kv tiles of 64
    const int nfull = (qb + 1) >> 6;      // maskless tiles
    const int cs = (nt + 3) >> 2;
    const int t0 = f * cs;
    const int t1 = min(nt, (f + 1) * cs);
    const ushort* kbase = k_ws + (size_t)b * SS * DD;
    const ushort* vbase = vT_ws + (size_t)b * DD * SS;

    short8 bufA[16], bufB[16];

#define LOADT(BUF, KT) do { \
    int kv0_ = (KT) * 64; \
    _Pragma("unroll") \
    for (int nf = 0; nf < 4; ++nf) { \
        const ushort* kp_ = kbase + (size_t)(kv0_ + nf * 16 + lr) * DD; \
        BUF[nf * 2 + 0] = *reinterpret_cast<const short8*>(kp_ + g * 8); \
        BUF[nf * 2 + 1] = *reinterpret_cast<const short8*>(kp_ + 32 + g * 8); \
    } \
    _Pragma("unroll") \
    for (int df = 0; df < 4; ++df) { \
        const ushort* vp_ = vbase + (size_t)(df * 16 + lr) * SS + kv0_; \
        BUF[8 + df * 2 + 0] = *reinterpret_cast<const short8*>(vp_ + g * 8); \
        BUF[8 + df * 2 + 1] = *reinterpret_cast<const short8*>(vp_ + 32 + g * 8); \
    } \
} while (0)

#define COMPUTE(BUF, KT) do { \
    int kv0_ = (KT) * 64; \
    f32x4 sfr[4]; \
    _Pragma("unroll") \
    for (int nf = 0; nf < 4; ++nf) { \
        f32x4 s_ = (f32x4)(0.0f); \
        s_ = __builtin_amdgcn_mfma_f32_16x16x32_bf16(BUF[nf * 2 + 0], qf0, s_, 0, 0, 0); \
        s_ = __builtin_amdgcn_mfma_f32_16x16x32_bf16(BUF[nf * 2 + 1], qf1, s_, 0, 0, 0); \
        sfr[nf] = s_; \
    } \
    _Pragma("unroll") \
    for (int nf = 0; nf < 4; ++nf) sfr[nf] *= sc; \
    if ((KT) >= nfull) { \
        _Pragma("unroll") \
        for (int nf = 0; nf < 4; ++nf) \
            _Pragma("unroll") \
            for (int jr = 0; jr < 4; ++jr) \
                if (kv0_ + nf * 16 + 4 * g + jr > qb + lr) sfr[nf][jr] = -1e30f; \
    } \
    float mt = fmaxf(fmaxf(fmaxf(sfr[0][0], sfr[0][1]), fmaxf(sfr[0][2], sfr[0][3])), \
                     fmaxf(fmaxf(sfr[1][0], sfr[1][1]), fmaxf(sfr[1][2], sfr[1][3]))); \
    mt = fmaxf(mt, fmaxf(fmaxf(fmaxf(sfr[2][0], sfr[2][1]), fmaxf(sfr[2][2], sfr[2][3])), \
                         fmaxf(fmaxf(sfr[3][0], sfr[3][1]), fmaxf(sfr[3][2], sfr[3][3])))); \
    mt = fmaxf(mt, __shfl_xor(mt, 16)); \
    mt = fmaxf(mt, __shfl_xor(mt, 32)); \
    float mn = fmaxf(m_r, mt); \
    float sf = exp2f(m_r - mn); \
    m_r = mn; \
    float ps = 0.0f; \
    uint32_t pk[8]; \
    _Pragma("unroll") \
    for (int nf = 0; nf < 4; ++nf) { \
        float e0_ = exp2f(sfr[nf][0] - mn); \
        float e1_ = exp2f(sfr[nf][1] - mn); \
        float e2_ = exp2f(sfr[nf][2] - mn); \
        float e3_ = exp2f(sfr[nf][3] - mn); \
        ps += (e0_ + e1_) + (e2_ + e3_); \
        pk[nf * 2 + 0] = cvtpk(e0_, e1_); \
        pk[nf * 2 + 1] = cvtpk(e2_, e3_); \
    } \
    ps += __shfl_xor(ps, 16); \
    ps += __shfl_xor(ps, 32); \
    l_r = l_r * sf + ps; \
    _Pragma("unroll") \
    for (int df = 0; df < 4; ++df) acc[df] *= sf; \
    _Pragma("unroll") \
    for (int nf = 0; nf < 4; ++nf) { \
        uint2 w_; w_.x = pk[nf * 2]; w_.y = pk[nf * 2 + 1]; \
        *reinterpret_cast<uint2*>(&P_lds[lr * 72 + nf * 16 + 4 * g]) = w_; \
    } \
    _Pragma("unroll") \
    for (int c = 0; c < 2; ++c) { \
        short8 pb_ = *reinterpret_cast<const short8*>(&P_lds[lr * 72 + c * 32 + g * 8]); \
        _Pragma("unroll") \
        for (int df = 0; df < 4; ++df) \
            acc[df] = __builtin_amdgcn_mfma_f32_16x16x32_bf16(BUF[8 + df * 2 + c], pb_, acc[df], 0, 0, 0); \
    } \
} while (0)

    if (t0 < t1) {
        LOADT(bufA, t0);
        int kt = t0;
        while (true) {
            if (kt + 1 < t1) LOADT(bufB, kt + 1);
            COMPUTE(bufA, kt);
            ++kt; if (kt >= t1) break;
            if (kt + 1 < t1) LOADT(bufA, kt + 1);
            COMPUTE(bufB, kt);
            ++kt; if (kt >= t1) break;
        }
    }

    // store partial: O^T bf16-packed along d: [32 dpairs][16 q], plus m,l
    const int pidx = ((b * 256 + qt) * 4 + f);
    uint32_t* po = pO32 + (size_t)pidx * 512;
#pragma unroll
    for (int df = 0; df < 4; ++df) {
        po[(df * 8 + 2 * g + 0) * 16 + lr] = cvtpk(acc[df][0], acc[df][1]);
        po[(df * 8 + 2 * g + 1) * 16 + lr] = cvtpk(acc[df][2], acc[df][3]);
    }
    if (g == 0) {
        pml[(size_t)pidx * 32 + lr] = m_r;
        pml[(size_t)pidx * 32 + 16 + lr] = l_r;
    }
}

// ---------- Combine partials ----------
__global__ __launch_bounds__(64) void combine_kernel(
    const uint32_t* __restrict__ pO32, const float* __restrict__ pml,
    float* __restrict__ out)
{
    const int t = threadIdx.x;
    const int q = t & 15, dblk = t >> 4;
    const int grp = blockIdx.x;          // b*256 + qt
    const int b = grp >> 8, qt = grp & 255;
    const int qb = qt * 16;

    float mf[4], lf[4];
#pragma unroll
    for (int f = 0; f < 4; ++f) {
        mf[f] = pml[(size_t)(grp * 4 + f) * 32 + q];
        lf[f] = pml[(size_t)(grp * 4 + f) * 32 + 16 + q];
    }
    float m = fmaxf(fmaxf(mf[0], mf[1]), fmaxf(mf[2], mf[3]));
    float w[4], l = 0.0f;
#pragma unroll
    for (int f = 0; f < 4; ++f) { w[f] = exp2f(mf[f] - m); l += w[f] * lf[f]; }

    float o[16];
#pragma unroll
    for (int i = 0; i < 16; ++i) o[i] = 0.0f;
#pragma unroll
    for (int f = 0; f < 4; ++f) {
        if (w[f] == 0.0f) continue;
        const uint32_t* src = pO32 + (size_t)(grp * 4 + f) * 512 + dblk * 128 + q;
#pragma unroll
        for (int r0 = 0; r0 < 8; ++r0) {
            uint32_t u = src[r0 * 16];
            o[2 * r0 + 0] += w[f] * bf2f_lo(u);
            o[2 * r0 + 1] += w[f] * bf2f_hi(u);
        }
    }
    float inv = 1.0f / l;
    float* op = out + ((size_t)b * SS + qb + q) * DD + dblk * 16;
#pragma unroll
    for (int i = 0; i < 4; ++i) {
        float4 st;
        st.x = o[4 * i + 0] * inv; st.y = o[4 * i + 1] * inv;
        st.z = o[4 * i + 2] * inv; st.w = o[4 * i + 3] * inv;
        *reinterpret_cast<float4*>(op + 4 * i) = st;
    }
}

extern "C" void kernel_launch(void* const* d_in, const int* in_sizes, int n_in,
                              void* d_out, int out_size, void* d_ws, size_t ws_size,
                              hipStream_t stream) {
    const float* x  = (const float*)d_in[0];
    const float* Wk = (const float*)d_in[1];
    const float* Wq = (const float*)d_in[2];
    const float* Wv = (const float*)d_in[3];
    ushort* q_ws  = (ushort*)d_ws;
    ushort* k_ws  = q_ws + (size_t)BB * SS * DD;
    ushort* vT_ws = k_ws + (size_t)BB * SS * DD;
    ushort* Wb    = vT_ws + (size_t)BB * SS * DD;
    uint32_t* pO32 = (uint32_t*)(Wb + 192 * 1024);          // 4096 * 512 u32 = 8 MB
    float* pml     = (float*)(pO32 + (size_t)4096 * 512);   // 4096 * 32 f32 = 512 KB
    float* out = (float*)d_out;

    hipLaunchKernelGGL(wconv_kernel, dim3(96), dim3(256), 0, stream, Wq, Wk, Wv, Wb);
    hipLaunchKernelGGL(proj_kernel, dim3(BB * SS / 64), dim3(256), 0, stream,
                       x, Wb, q_ws, k_ws, vT_ws);
    hipLaunchKernelGGL(attn_kernel, dim3(BB * SS / 16 * 4), dim3(64), 0, stream,
                       q_ws, k_ws, vT_ws, pO32, pml);
    hipLaunchKernelGGL(combine_kernel, dim3(BB * SS / 16), dim3(64), 0, stream,
                       pO32, pml, out);
}

// Round 5
// 137.664 us; speedup vs baseline: 1.4411x; 1.4411x over previous
//
#include <hip/hip_runtime.h>
#include <hip/hip_bf16.h>
#include <stdint.h>

#define BB 4
#define SS 4096
#define EE 1024
#define DD 64

typedef __attribute__((ext_vector_type(8))) short short8;
typedef __attribute__((ext_vector_type(4))) float f32x4;

__device__ inline uint32_t cvtpk(float lo, float hi) {
    uint32_t r;
    asm("v_cvt_pk_bf16_f32 %0, %1, %2" : "=v"(r) : "v"(lo), "v"(hi));
    return r;
}
__device__ inline float bf2f_lo(uint32_t u) {
    union { uint32_t u; float f; } v; v.u = u << 16; return v.f;
}
__device__ inline float bf2f_hi(uint32_t u) {
    union { uint32_t u; float f; } v; v.u = u & 0xFFFF0000u; return v.f;
}

#define SWZ16(r, bc) ((bc) ^ (((r) & 7) << 4))

// ---------- W f32 -> bf16 concat [192][1024] ----------
__global__ __launch_bounds__(256) void wconv_kernel(
    const float* __restrict__ Wq, const float* __restrict__ Wk,
    const float* __restrict__ Wv, ushort* __restrict__ Wb)
{
    int tid = blockIdx.x * 256 + threadIdx.x;
    int sel = tid >> 13;
    int off = (tid & 8191) * 8;
    const float* src = (sel == 0) ? Wq : ((sel == 1) ? Wk : Wv);
    float4 a = *reinterpret_cast<const float4*>(src + off);
    float4 b = *reinterpret_cast<const float4*>(src + off + 4);
    uint4 o;
    o.x = cvtpk(a.x, a.y); o.y = cvtpk(a.z, a.w);
    o.z = cvtpk(b.x, b.y); o.w = cvtpk(b.z, b.w);
    *reinterpret_cast<uint4*>(Wb + (size_t)sel * 65536 + off) = o;
}

// ---------- Projection: M-tile 32, grid 512 (2 blocks/CU) ----------
__global__ __launch_bounds__(256) void proj_kernel(
    const float* __restrict__ x, const ushort* __restrict__ Wb,
    ushort* __restrict__ q_ws, ushort* __restrict__ k_ws, ushort* __restrict__ vT_ws)
{
    __shared__ __align__(16) ushort x_lds[32 * 64];
    __shared__ __align__(16) ushort w_lds[192 * 64];
    const int t = threadIdx.x;
    const int wid = t >> 6, lane = t & 63, g = lane >> 4, lr = lane & 15;
    const int m0 = blockIdx.x * 32;

    f32x4 acc[3][2];
#pragma unroll
    for (int ni = 0; ni < 3; ++ni)
#pragma unroll
        for (int mi = 0; mi < 2; ++mi) acc[ni][mi] = (f32x4)(0.0f);

    float4 xr[2];
    uint4 wr[6];

#define LOADX(E0) do { \
    _Pragma("unroll") \
    for (int i = 0; i < 2; ++i) { \
        int idx = i * 256 + t; int row = idx >> 4, c4 = idx & 15; \
        xr[i] = *reinterpret_cast<const float4*>(&x[(size_t)(m0 + row) * EE + (E0) + c4 * 4]); \
    } \
} while (0)
#define LOADW(E0) do { \
    _Pragma("unroll") \
    for (int i = 0; i < 6; ++i) { \
        int idx = i * 256 + t; int row = idx >> 3, c8 = idx & 7; \
        wr[i] = *reinterpret_cast<const uint4*>(&Wb[(size_t)row * EE + (E0) + c8 * 8]); \
    } \
} while (0)

    LOADX(0); LOADW(0);
    for (int e0 = 0; e0 < EE; e0 += 64) {
#pragma unroll
        for (int i = 0; i < 2; ++i) {
            int idx = i * 256 + t; int row = idx >> 4, c4 = idx & 15;
            uint2 p; p.x = cvtpk(xr[i].x, xr[i].y); p.y = cvtpk(xr[i].z, xr[i].w);
            *reinterpret_cast<uint2*>((char*)x_lds + row * 128 + SWZ16(row, c4 * 8)) = p;
        }
#pragma unroll
        for (int i = 0; i < 6; ++i) {
            int idx = i * 256 + t; int row = idx >> 3, c8 = idx & 7;
            *reinterpret_cast<uint4*>((char*)w_lds + row * 128 + SWZ16(row, c8 * 16)) = wr[i];
        }
        __syncthreads();
        if (e0 + 64 < EE) { LOADX(e0 + 64); LOADW(e0 + 64); }

        short8 af[3][2], bf[2][2];
#pragma unroll
        for (int ni = 0; ni < 3; ++ni)
#pragma unroll
            for (int c = 0; c < 2; ++c) {
                int row = wid * 48 + ni * 16 + lr;
                af[ni][c] = *reinterpret_cast<const short8*>((const char*)w_lds + row * 128 + SWZ16(row, c * 64 + g * 16));
            }
#pragma unroll
        for (int mi = 0; mi < 2; ++mi)
#pragma unroll
            for (int c = 0; c < 2; ++c) {
                int row = mi * 16 + lr;
                bf[mi][c] = *reinterpret_cast<const short8*>((const char*)x_lds + row * 128 + SWZ16(row, c * 64 + g * 16));
            }
#pragma unroll
        for (int ni = 0; ni < 3; ++ni)
#pragma unroll
            for (int mi = 0; mi < 2; ++mi)
#pragma unroll
                for (int c = 0; c < 2; ++c)
                    acc[ni][mi] = __builtin_amdgcn_mfma_f32_16x16x32_bf16(af[ni][c], bf[mi][c], acc[ni][mi], 0, 0, 0);
        __syncthreads();
    }

#pragma unroll
    for (int ni = 0; ni < 3; ++ni) {
        int n0 = wid * 48 + ni * 16 + 4 * g;
        int sel = n0 >> 6, d0 = n0 & 63;
#pragma unroll
        for (int mi = 0; mi < 2; ++mi) {
            int m = m0 + mi * 16 + lr;
            int b = m >> 12, s = m & (SS - 1);
            uint2 p;
            p.x = cvtpk(acc[ni][mi][0], acc[ni][mi][1]);
            p.y = cvtpk(acc[ni][mi][2], acc[ni][mi][3]);
            if (sel == 0) {
                *reinterpret_cast<uint2*>(q_ws + ((size_t)b * SS + s) * DD + d0) = p;
            } else if (sel == 1) {
                *reinterpret_cast<uint2*>(k_ws + ((size_t)b * SS + s) * DD + d0) = p;
            } else {
                vT_ws[((size_t)b * DD + d0 + 0) * SS + s] = (ushort)(p.x & 0xFFFF);
                vT_ws[((size_t)b * DD + d0 + 1) * SS + s] = (ushort)(p.x >> 16);
                vT_ws[((size_t)b * DD + d0 + 2) * SS + s] = (ushort)(p.y & 0xFFFF);
                vT_ws[((size_t)b * DD + d0 + 3) * SS + s] = (ushort)(p.y >> 16);
            }
        }
    }
}

// ---------- Flash attention, split-KV: 1 wave per (q-tile, kv-fragment) ----------
__global__ __launch_bounds__(64) void attn_kernel(
    const ushort* __restrict__ q_ws, const ushort* __restrict__ k_ws,
    const ushort* __restrict__ vT_ws, uint32_t* __restrict__ pO32,
    float* __restrict__ pml)
{
    __shared__ __align__(16) ushort P_lds[16 * 72];
    const int lane = threadIdx.x, g = lane >> 4, lr = lane & 15;
    const int bid = blockIdx.x;
    const int f = bid & 3;
    const int b = (bid >> 2) & 3;
    const int qt = 255 - (bid >> 4);      // heavy q-tiles first
    const int qb = qt * 16;

    const ushort* qp = q_ws + ((size_t)b * SS + qb + lr) * DD;
    short8 qf0 = *reinterpret_cast<const short8*>(qp + g * 8);
    short8 qf1 = *reinterpret_cast<const short8*>(qp + 32 + g * 8);

    float m_r = -1e30f, l_r = 0.0f;
    f32x4 acc[4];
#pragma unroll
    for (int i = 0; i < 4; ++i) acc[i] = (f32x4)(0.0f);

    const float sc = 0.125f * 1.44269504f;
    const int nt = (qb + 79) >> 6;        // total kv tiles of 64
    const int nfull = (qb + 1) >> 6;      // maskless tiles
    const int cs = (nt + 3) >> 2;
    const int t0 = f * cs;
    const int t1 = min(nt, (f + 1) * cs);
    const ushort* kbase = k_ws + (size_t)b * SS * DD;
    const ushort* vbase = vT_ws + (size_t)b * DD * SS;

    short8 bufA[16], bufB[16];

#define LOADT(BUF, KT) do { \
    int kv0_ = (KT) * 64; \
    _Pragma("unroll") \
    for (int nf = 0; nf < 4; ++nf) { \
        const ushort* kp_ = kbase + (size_t)(kv0_ + nf * 16 + lr) * DD; \
        BUF[nf * 2 + 0] = *reinterpret_cast<const short8*>(kp_ + g * 8); \
        BUF[nf * 2 + 1] = *reinterpret_cast<const short8*>(kp_ + 32 + g * 8); \
    } \
    _Pragma("unroll") \
    for (int df = 0; df < 4; ++df) { \
        const ushort* vp_ = vbase + (size_t)(df * 16 + lr) * SS + kv0_; \
        BUF[8 + df * 2 + 0] = *reinterpret_cast<const short8*>(vp_ + g * 8); \
        BUF[8 + df * 2 + 1] = *reinterpret_cast<const short8*>(vp_ + 32 + g * 8); \
    } \
} while (0)

#define COMPUTE(BUF, KT) do { \
    int kv0_ = (KT) * 64; \
    f32x4 sfr[4]; \
    _Pragma("unroll") \
    for (int nf = 0; nf < 4; ++nf) { \
        f32x4 s_ = (f32x4)(0.0f); \
        s_ = __builtin_amdgcn_mfma_f32_16x16x32_bf16(BUF[nf * 2 + 0], qf0, s_, 0, 0, 0); \
        s_ = __builtin_amdgcn_mfma_f32_16x16x32_bf16(BUF[nf * 2 + 1], qf1, s_, 0, 0, 0); \
        sfr[nf] = s_; \
    } \
    _Pragma("unroll") \
    for (int nf = 0; nf < 4; ++nf) sfr[nf] *= sc; \
    if ((KT) >= nfull) { \
        _Pragma("unroll") \
        for (int nf = 0; nf < 4; ++nf) \
            _Pragma("unroll") \
            for (int jr = 0; jr < 4; ++jr) \
                if (kv0_ + nf * 16 + 4 * g + jr > qb + lr) sfr[nf][jr] = -1e30f; \
    } \
    float mt = fmaxf(fmaxf(fmaxf(sfr[0][0], sfr[0][1]), fmaxf(sfr[0][2], sfr[0][3])), \
                     fmaxf(fmaxf(sfr[1][0], sfr[1][1]), fmaxf(sfr[1][2], sfr[1][3]))); \
    mt = fmaxf(mt, fmaxf(fmaxf(fmaxf(sfr[2][0], sfr[2][1]), fmaxf(sfr[2][2], sfr[2][3])), \
                         fmaxf(fmaxf(sfr[3][0], sfr[3][1]), fmaxf(sfr[3][2], sfr[3][3])))); \
    mt = fmaxf(mt, __shfl_xor(mt, 16)); \
    mt = fmaxf(mt, __shfl_xor(mt, 32)); \
    float mn = fmaxf(m_r, mt); \
    float sf = exp2f(m_r - mn); \
    m_r = mn; \
    float ps = 0.0f; \
    uint32_t pk[8]; \
    _Pragma("unroll") \
    for (int nf = 0; nf < 4; ++nf) { \
        float e0_ = exp2f(sfr[nf][0] - mn); \
        float e1_ = exp2f(sfr[nf][1] - mn); \
        float e2_ = exp2f(sfr[nf][2] - mn); \
        float e3_ = exp2f(sfr[nf][3] - mn); \
        ps += (e0_ + e1_) + (e2_ + e3_); \
        pk[nf * 2 + 0] = cvtpk(e0_, e1_); \
        pk[nf * 2 + 1] = cvtpk(e2_, e3_); \
    } \
    ps += __shfl_xor(ps, 16); \
    ps += __shfl_xor(ps, 32); \
    l_r = l_r * sf + ps; \
    _Pragma("unroll") \
    for (int df = 0; df < 4; ++df) acc[df] *= sf; \
    _Pragma("unroll") \
    for (int nf = 0; nf < 4; ++nf) { \
        uint2 w_; w_.x = pk[nf * 2]; w_.y = pk[nf * 2 + 1]; \
        *reinterpret_cast<uint2*>(&P_lds[lr * 72 + nf * 16 + 4 * g]) = w_; \
    } \
    /* cross-lane LDS RAW fence: the reads below consume other lanes' writes. */ \
    asm volatile("s_waitcnt lgkmcnt(0)" ::: "memory"); \
    __builtin_amdgcn_sched_barrier(0); \
    _Pragma("unroll") \
    for (int c = 0; c < 2; ++c) { \
        short8 pb_ = *reinterpret_cast<const short8*>(&P_lds[lr * 72 + c * 32 + g * 8]); \
        _Pragma("unroll") \
        for (int df = 0; df < 4; ++df) \
            acc[df] = __builtin_amdgcn_mfma_f32_16x16x32_bf16(BUF[8 + df * 2 + c], pb_, acc[df], 0, 0, 0); \
    } \
} while (0)

    if (t0 < t1) {
        LOADT(bufA, t0);
        int kt = t0;
        while (true) {
            if (kt + 1 < t1) LOADT(bufB, kt + 1);
            COMPUTE(bufA, kt);
            ++kt; if (kt >= t1) break;
            if (kt + 1 < t1) LOADT(bufA, kt + 1);
            COMPUTE(bufB, kt);
            ++kt; if (kt >= t1) break;
        }
    }

    // store partial: O^T bf16-packed along d: [32 dpairs][16 q], plus m,l
    const int pidx = ((b * 256 + qt) * 4 + f);
    uint32_t* po = pO32 + (size_t)pidx * 512;
#pragma unroll
    for (int df = 0; df < 4; ++df) {
        po[(df * 8 + 2 * g + 0) * 16 + lr] = cvtpk(acc[df][0], acc[df][1]);
        po[(df * 8 + 2 * g + 1) * 16 + lr] = cvtpk(acc[df][2], acc[df][3]);
    }
    if (g == 0) {
        pml[(size_t)pidx * 32 + lr] = m_r;
        pml[(size_t)pidx * 32 + 16 + lr] = l_r;
    }
}

// ---------- Combine partials ----------
__global__ __launch_bounds__(64) void combine_kernel(
    const uint32_t* __restrict__ pO32, const float* __restrict__ pml,
    float* __restrict__ out)
{
    const int t = threadIdx.x;
    const int q = t & 15, dblk = t >> 4;
    const int grp = blockIdx.x;          // b*256 + qt
    const int b = grp >> 8, qt = grp & 255;
    const int qb = qt * 16;

    float mf[4], lf[4];
#pragma unroll
    for (int f = 0; f < 4; ++f) {
        mf[f] = pml[(size_t)(grp * 4 + f) * 32 + q];
        lf[f] = pml[(size_t)(grp * 4 + f) * 32 + 16 + q];
    }
    float m = fmaxf(fmaxf(mf[0], mf[1]), fmaxf(mf[2], mf[3]));
    float w[4], l = 0.0f;
#pragma unroll
    for (int f = 0; f < 4; ++f) { w[f] = exp2f(mf[f] - m); l += w[f] * lf[f]; }

    float o[16];
#pragma unroll
    for (int i = 0; i < 16; ++i) o[i] = 0.0f;
#pragma unroll
    for (int f = 0; f < 4; ++f) {
        if (w[f] == 0.0f) continue;
        const uint32_t* src = pO32 + (size_t)(grp * 4 + f) * 512 + dblk * 128 + q;
#pragma unroll
        for (int r0 = 0; r0 < 8; ++r0) {
            uint32_t u = src[r0 * 16];
            o[2 * r0 + 0] += w[f] * bf2f_lo(u);
            o[2 * r0 + 1] += w[f] * bf2f_hi(u);
        }
    }
    float inv = 1.0f / l;
    float* op = out + ((size_t)b * SS + qb + q) * DD + dblk * 16;
#pragma unroll
    for (int i = 0; i < 4; ++i) {
        float4 st;
        st.x = o[4 * i + 0] * inv; st.y = o[4 * i + 1] * inv;
        st.z = o[4 * i + 2] * inv; st.w = o[4 * i + 3] * inv;
        *reinterpret_cast<float4*>(op + 4 * i) = st;
    }
}

extern "C" void kernel_launch(void* const* d_in, const int* in_sizes, int n_in,
                              void* d_out, int out_size, void* d_ws, size_t ws_size,
                              hipStream_t stream) {
    const float* x  = (const float*)d_in[0];
    const float* Wk = (const float*)d_in[1];
    const float* Wq = (const float*)d_in[2];
    const float* Wv = (const float*)d_in[3];
    ushort* q_ws  = (ushort*)d_ws;
    ushort* k_ws  = q_ws + (size_t)BB * SS * DD;
    ushort* vT_ws = k_ws + (size_t)BB * SS * DD;
    ushort* Wb    = vT_ws + (size_t)BB * SS * DD;
    uint32_t* pO32 = (uint32_t*)(Wb + 192 * 1024);          // 4096 * 512 u32 = 8 MB
    float* pml     = (float*)(pO32 + (size_t)4096 * 512);   // 4096 * 32 f32 = 512 KB
    float* out = (float*)d_out;

    hipLaunchKernelGGL(wconv_kernel, dim3(96), dim3(256), 0, stream, Wq, Wk, Wv, Wb);
    hipLaunchKernelGGL(proj_kernel, dim3(BB * SS / 32), dim3(256), 0, stream,
                       x, Wb, q_ws, k_ws, vT_ws);
    hipLaunchKernelGGL(attn_kernel, dim3(BB * SS / 16 * 4), dim3(64), 0, stream,
                       q_ws, k_ws, vT_ws, pO32, pml);
    hipLaunchKernelGGL(combine_kernel, dim3(BB * SS / 16), dim3(64), 0, stream,
                       pO32, pml, out);
}

// Round 6
// 101.676 us; speedup vs baseline: 1.9512x; 1.3539x over previous
//
#include <hip/hip_runtime.h>
#include <hip/hip_bf16.h>
#include <stdint.h>

#define BB 4
#define SS 4096
#define EE 1024
#define DD 64

typedef __attribute__((ext_vector_type(8))) short short8;
typedef __attribute__((ext_vector_type(4))) float f32x4;

__device__ inline uint32_t cvtpk(float lo, float hi) {
    uint32_t r;
    asm("v_cvt_pk_bf16_f32 %0, %1, %2" : "=v"(r) : "v"(lo), "v"(hi));
    return r;
}
__device__ inline float bf2f_lo(uint32_t u) {
    union { uint32_t u; float f; } v; v.u = u << 16; return v.f;
}
__device__ inline float bf2f_hi(uint32_t u) {
    union { uint32_t u; float f; } v; v.u = u & 0xFFFF0000u; return v.f;
}

#define GL16(g, l) __builtin_amdgcn_global_load_lds( \
    (const __attribute__((address_space(1))) void*)(g), \
    (__attribute__((address_space(3))) void*)(l), 16, 0, 0)

// ---------- W f32 -> bf16 concat [192][1024]: rows 0-63 Wq, 64-127 Wk, 128-191 Wv ----------
__global__ __launch_bounds__(256) void wconv_kernel(
    const float* __restrict__ Wq, const float* __restrict__ Wk,
    const float* __restrict__ Wv, ushort* __restrict__ Wb)
{
    int tid = blockIdx.x * 256 + threadIdx.x;
    int sel = tid >> 13;
    int off = (tid & 8191) * 8;
    const float* src = (sel == 0) ? Wq : ((sel == 1) ? Wk : Wv);
    float4 a = *reinterpret_cast<const float4*>(src + off);
    float4 b = *reinterpret_cast<const float4*>(src + off + 4);
    uint4 o;
    o.x = cvtpk(a.x, a.y); o.y = cvtpk(a.z, a.w);
    o.z = cvtpk(b.x, b.y); o.w = cvtpk(b.z, b.w);
    *reinterpret_cast<uint4*>(Wb + (size_t)sel * 65536 + off) = o;
}

// ---------- Projection: async gload_lds pipeline, 3-deep, counted vmcnt ----------
// M-tile 64 (grid 256, 4 waves). K-step 32. Per tile: x 64x32 f32 (8 KB, swizzled
// source) + W 192x32 bf16 (12 KB). 3 buffers = 60 KB LDS. 5 gload_lds/thread/tile;
// steady state waits vmcnt(10) -> 2 tiles (10 loads/wave) always in flight.
__global__ __launch_bounds__(256) void proj_kernel(
    const float* __restrict__ x, const ushort* __restrict__ Wb,
    ushort* __restrict__ q_ws, ushort* __restrict__ k_ws, ushort* __restrict__ vT_ws)
{
    __shared__ __align__(16) char smem[3 * 20480];
    const int t = threadIdx.x;
    const int wid = t >> 6, lane = t & 63, g = lane >> 4, lr = lane & 15;
    const int m0 = blockIdx.x * 64;
    const int NT = EE / 32;   // 32 tiles

    f32x4 acc[3][4];
#pragma unroll
    for (int ni = 0; ni < 3; ++ni)
#pragma unroll
        for (int mi = 0; mi < 4; ++mi) acc[ni][mi] = (f32x4)(0.0f);

#define STAGE(KT, BUFI) do { \
    char* xb_ = smem + (BUFI) * 20480; \
    char* wb_ = xb_ + 8192; \
    int e0_ = (KT) * 32; \
    _Pragma("unroll") \
    for (int i = 0; i < 2; ++i) { \
        int v = i * 256 + t; int row = v >> 3, c = v & 7; \
        GL16(&x[(size_t)(m0 + row) * EE + e0_ + ((c ^ (row & 7)) << 2)], xb_ + v * 16); \
    } \
    _Pragma("unroll") \
    for (int i = 0; i < 3; ++i) { \
        int v = i * 256 + t; int row = v >> 2, u = v & 3; \
        GL16(&Wb[(size_t)row * EE + e0_ + ((u ^ (row & 3)) << 3)], wb_ + v * 16); \
    } \
} while (0)

    STAGE(0, 0); STAGE(1, 1); STAGE(2, 2);

    for (int kt = 0; kt < NT; ++kt) {
        // wait for tile kt (leave tiles kt+1, kt+2 = 10 loads in flight)
        asm volatile("s_waitcnt vmcnt(10)" ::: "memory");
        __builtin_amdgcn_s_barrier();
        __builtin_amdgcn_sched_barrier(0);

        const char* xb = smem + (kt % 3) * 20480;
        const char* wb = xb + 8192;

        short8 af[3], bf[4];
#pragma unroll
        for (int ni = 0; ni < 3; ++ni) {
            int row = wid * 48 + ni * 16 + lr;
            af[ni] = *reinterpret_cast<const short8*>(wb + row * 64 + ((g ^ (lr & 3)) << 4));
        }
#pragma unroll
        for (int mi = 0; mi < 4; ++mi) {
            int row = mi * 16 + lr;
            int u0 = (2 * g) ^ (lr & 7);
            f32x4 lo = *reinterpret_cast<const f32x4*>(xb + row * 128 + u0 * 16);
            f32x4 hi = *reinterpret_cast<const f32x4*>(xb + row * 128 + (u0 ^ 1) * 16);
            union { short8 s; uint32_t u[4]; } p;
            p.u[0] = cvtpk(lo[0], lo[1]); p.u[1] = cvtpk(lo[2], lo[3]);
            p.u[2] = cvtpk(hi[0], hi[1]); p.u[3] = cvtpk(hi[2], hi[3]);
            bf[mi] = p.s;
        }
#pragma unroll
        for (int ni = 0; ni < 3; ++ni)
#pragma unroll
            for (int mi = 0; mi < 4; ++mi)
                acc[ni][mi] = __builtin_amdgcn_mfma_f32_16x16x32_bf16(af[ni], bf[mi], acc[ni][mi], 0, 0, 0);

        // all our LDS reads done before any wave overwrites this buffer
        asm volatile("s_waitcnt lgkmcnt(0)" ::: "memory");
        __builtin_amdgcn_sched_barrier(0);
        __builtin_amdgcn_s_barrier();
        __builtin_amdgcn_sched_barrier(0);

        int nx = (kt + 3 < NT) ? kt + 3 : NT - 1;   // clamped dummy keeps vmcnt uniform
        STAGE(nx, kt % 3);
    }

    // epilogue: D[n][m]: n = wid*48+ni*16+4g+jr -> (sel,d), m = m0+mi*16+lr -> (b,s)
#pragma unroll
    for (int ni = 0; ni < 3; ++ni) {
        int n0 = wid * 48 + ni * 16 + 4 * g;
        int sel = n0 >> 6, d0 = n0 & 63;
#pragma unroll
        for (int mi = 0; mi < 4; ++mi) {
            int m = m0 + mi * 16 + lr;
            int b = m >> 12, s = m & (SS - 1);
            uint2 p;
            p.x = cvtpk(acc[ni][mi][0], acc[ni][mi][1]);
            p.y = cvtpk(acc[ni][mi][2], acc[ni][mi][3]);
            if (sel == 0) {
                *reinterpret_cast<uint2*>(q_ws + ((size_t)b * SS + s) * DD + d0) = p;
            } else if (sel == 1) {
                *reinterpret_cast<uint2*>(k_ws + ((size_t)b * SS + s) * DD + d0) = p;
            } else {
                vT_ws[((size_t)b * DD + d0 + 0) * SS + s] = (ushort)(p.x & 0xFFFF);
                vT_ws[((size_t)b * DD + d0 + 1) * SS + s] = (ushort)(p.x >> 16);
                vT_ws[((size_t)b * DD + d0 + 2) * SS + s] = (ushort)(p.y & 0xFFFF);
                vT_ws[((size_t)b * DD + d0 + 3) * SS + s] = (ushort)(p.y >> 16);
            }
        }
    }
}

// ---------- Flash attention, split-KV: 1 wave per (q-tile, kv-fragment) ----------
__global__ __launch_bounds__(64) void attn_kernel(
    const ushort* __restrict__ q_ws, const ushort* __restrict__ k_ws,
    const ushort* __restrict__ vT_ws, uint32_t* __restrict__ pO32,
    float* __restrict__ pml)
{
    __shared__ __align__(16) ushort P_lds[16 * 72];
    const int lane = threadIdx.x, g = lane >> 4, lr = lane & 15;
    const int bid = blockIdx.x;
    const int f = bid & 3;
    const int b = (bid >> 2) & 3;
    const int qt = 255 - (bid >> 4);      // heavy q-tiles first
    const int qb = qt * 16;

    const ushort* qp = q_ws + ((size_t)b * SS + qb + lr) * DD;
    short8 qf0 = *reinterpret_cast<const short8*>(qp + g * 8);
    short8 qf1 = *reinterpret_cast<const short8*>(qp + 32 + g * 8);

    float m_r = -1e30f, l_r = 0.0f;
    f32x4 acc[4];
#pragma unroll
    for (int i = 0; i < 4; ++i) acc[i] = (f32x4)(0.0f);

    const float sc = 0.125f * 1.44269504f;
    const int nt = (qb + 79) >> 6;        // total kv tiles of 64
    const int nfull = (qb + 1) >> 6;      // maskless tiles
    const int cs = (nt + 3) >> 2;
    const int t0 = f * cs;
    const int t1 = min(nt, (f + 1) * cs);
    const ushort* kbase = k_ws + (size_t)b * SS * DD;
    const ushort* vbase = vT_ws + (size_t)b * DD * SS;

    short8 bufA[16], bufB[16];

#define LOADT(BUF, KT) do { \
    int kv0_ = (KT) * 64; \
    _Pragma("unroll") \
    for (int nf = 0; nf < 4; ++nf) { \
        const ushort* kp_ = kbase + (size_t)(kv0_ + nf * 16 + lr) * DD; \
        BUF[nf * 2 + 0] = *reinterpret_cast<const short8*>(kp_ + g * 8); \
        BUF[nf * 2 + 1] = *reinterpret_cast<const short8*>(kp_ + 32 + g * 8); \
    } \
    _Pragma("unroll") \
    for (int df = 0; df < 4; ++df) { \
        const ushort* vp_ = vbase + (size_t)(df * 16 + lr) * SS + kv0_; \
        BUF[8 + df * 2 + 0] = *reinterpret_cast<const short8*>(vp_ + g * 8); \
        BUF[8 + df * 2 + 1] = *reinterpret_cast<const short8*>(vp_ + 32 + g * 8); \
    } \
} while (0)

#define COMPUTE(BUF, KT) do { \
    int kv0_ = (KT) * 64; \
    f32x4 sfr[4]; \
    _Pragma("unroll") \
    for (int nf = 0; nf < 4; ++nf) { \
        f32x4 s_ = (f32x4)(0.0f); \
        s_ = __builtin_amdgcn_mfma_f32_16x16x32_bf16(BUF[nf * 2 + 0], qf0, s_, 0, 0, 0); \
        s_ = __builtin_amdgcn_mfma_f32_16x16x32_bf16(BUF[nf * 2 + 1], qf1, s_, 0, 0, 0); \
        sfr[nf] = s_; \
    } \
    _Pragma("unroll") \
    for (int nf = 0; nf < 4; ++nf) sfr[nf] *= sc; \
    if ((KT) >= nfull) { \
        _Pragma("unroll") \
        for (int nf = 0; nf < 4; ++nf) \
            _Pragma("unroll") \
            for (int jr = 0; jr < 4; ++jr) \
                if (kv0_ + nf * 16 + 4 * g + jr > qb + lr) sfr[nf][jr] = -1e30f; \
    } \
    float mt = fmaxf(fmaxf(fmaxf(sfr[0][0], sfr[0][1]), fmaxf(sfr[0][2], sfr[0][3])), \
                     fmaxf(fmaxf(sfr[1][0], sfr[1][1]), fmaxf(sfr[1][2], sfr[1][3]))); \
    mt = fmaxf(mt, fmaxf(fmaxf(fmaxf(sfr[2][0], sfr[2][1]), fmaxf(sfr[2][2], sfr[2][3])), \
                         fmaxf(fmaxf(sfr[3][0], sfr[3][1]), fmaxf(sfr[3][2], sfr[3][3])))); \
    mt = fmaxf(mt, __shfl_xor(mt, 16)); \
    mt = fmaxf(mt, __shfl_xor(mt, 32)); \
    float mn = fmaxf(m_r, mt); \
    float sf = exp2f(m_r - mn); \
    m_r = mn; \
    float ps = 0.0f; \
    uint32_t pk[8]; \
    _Pragma("unroll") \
    for (int nf = 0; nf < 4; ++nf) { \
        float e0_ = exp2f(sfr[nf][0] - mn); \
        float e1_ = exp2f(sfr[nf][1] - mn); \
        float e2_ = exp2f(sfr[nf][2] - mn); \
        float e3_ = exp2f(sfr[nf][3] - mn); \
        ps += (e0_ + e1_) + (e2_ + e3_); \
        pk[nf * 2 + 0] = cvtpk(e0_, e1_); \
        pk[nf * 2 + 1] = cvtpk(e2_, e3_); \
    } \
    ps += __shfl_xor(ps, 16); \
    ps += __shfl_xor(ps, 32); \
    l_r = l_r * sf + ps; \
    _Pragma("unroll") \
    for (int df = 0; df < 4; ++df) acc[df] *= sf; \
    _Pragma("unroll") \
    for (int nf = 0; nf < 4; ++nf) { \
        uint2 w_; w_.x = pk[nf * 2]; w_.y = pk[nf * 2 + 1]; \
        *reinterpret_cast<uint2*>(&P_lds[lr * 72 + nf * 16 + 4 * g]) = w_; \
    } \
    /* cross-lane LDS RAW fence: the reads below consume other lanes' writes. */ \
    asm volatile("s_waitcnt lgkmcnt(0)" ::: "memory"); \
    __builtin_amdgcn_sched_barrier(0); \
    _Pragma("unroll") \
    for (int c = 0; c < 2; ++c) { \
        short8 pb_ = *reinterpret_cast<const short8*>(&P_lds[lr * 72 + c * 32 + g * 8]); \
        _Pragma("unroll") \
        for (int df = 0; df < 4; ++df) \
            acc[df] = __builtin_amdgcn_mfma_f32_16x16x32_bf16(BUF[8 + df * 2 + c], pb_, acc[df], 0, 0, 0); \
    } \
} while (0)

    if (t0 < t1) {
        LOADT(bufA, t0);
        int kt = t0;
        while (true) {
            if (kt + 1 < t1) LOADT(bufB, kt + 1);
            COMPUTE(bufA, kt);
            ++kt; if (kt >= t1) break;
            if (kt + 1 < t1) LOADT(bufA, kt + 1);
            COMPUTE(bufB, kt);
            ++kt; if (kt >= t1) break;
        }
    }

    // store partial: O^T bf16-packed along d: [32 dpairs][16 q], plus m,l
    const int pidx = ((b * 256 + qt) * 4 + f);
    uint32_t* po = pO32 + (size_t)pidx * 512;
#pragma unroll
    for (int df = 0; df < 4; ++df) {
        po[(df * 8 + 2 * g + 0) * 16 + lr] = cvtpk(acc[df][0], acc[df][1]);
        po[(df * 8 + 2 * g + 1) * 16 + lr] = cvtpk(acc[df][2], acc[df][3]);
    }
    if (g == 0) {
        pml[(size_t)pidx * 32 + lr] = m_r;
        pml[(size_t)pidx * 32 + 16 + lr] = l_r;
    }
}

// ---------- Combine partials ----------
__global__ __launch_bounds__(64) void combine_kernel(
    const uint32_t* __restrict__ pO32, const float* __restrict__ pml,
    float* __restrict__ out)
{
    const int t = threadIdx.x;
    const int q = t & 15, dblk = t >> 4;
    const int grp = blockIdx.x;          // b*256 + qt
    const int b = grp >> 8, qt = grp & 255;
    const int qb = qt * 16;

    float mf[4], lf[4];
#pragma unroll
    for (int f = 0; f < 4; ++f) {
        mf[f] = pml[(size_t)(grp * 4 + f) * 32 + q];
        lf[f] = pml[(size_t)(grp * 4 + f) * 32 + 16 + q];
    }
    float m = fmaxf(fmaxf(mf[0], mf[1]), fmaxf(mf[2], mf[3]));
    float w[4], l = 0.0f;
#pragma unroll
    for (int f = 0; f < 4; ++f) { w[f] = exp2f(mf[f] - m); l += w[f] * lf[f]; }

    float o[16];
#pragma unroll
    for (int i = 0; i < 16; ++i) o[i] = 0.0f;
#pragma unroll
    for (int f = 0; f < 4; ++f) {
        if (w[f] == 0.0f) continue;
        const uint32_t* src = pO32 + (size_t)(grp * 4 + f) * 512 + dblk * 128 + q;
#pragma unroll
        for (int r0 = 0; r0 < 8; ++r0) {
            uint32_t u = src[r0 * 16];
            o[2 * r0 + 0] += w[f] * bf2f_lo(u);
            o[2 * r0 + 1] += w[f] * bf2f_hi(u);
        }
    }
    float inv = 1.0f / l;
    float* op = out + ((size_t)b * SS + qb + q) * DD + dblk * 16;
#pragma unroll
    for (int i = 0; i < 4; ++i) {
        float4 st;
        st.x = o[4 * i + 0] * inv; st.y = o[4 * i + 1] * inv;
        st.z = o[4 * i + 2] * inv; st.w = o[4 * i + 3] * inv;
        *reinterpret_cast<float4*>(op + 4 * i) = st;
    }
}

extern "C" void kernel_launch(void* const* d_in, const int* in_sizes, int n_in,
                              void* d_out, int out_size, void* d_ws, size_t ws_size,
                              hipStream_t stream) {
    const float* x  = (const float*)d_in[0];
    const float* Wk = (const float*)d_in[1];
    const float* Wq = (const float*)d_in[2];
    const float* Wv = (const float*)d_in[3];
    ushort* q_ws  = (ushort*)d_ws;
    ushort* k_ws  = q_ws + (size_t)BB * SS * DD;
    ushort* vT_ws = k_ws + (size_t)BB * SS * DD;
    ushort* Wb    = vT_ws + (size_t)BB * SS * DD;
    uint32_t* pO32 = (uint32_t*)(Wb + 192 * 1024);          // 4096 * 512 u32 = 8 MB
    float* pml     = (float*)(pO32 + (size_t)4096 * 512);   // 4096 * 32 f32 = 512 KB
    float* out = (float*)d_out;

    hipLaunchKernelGGL(wconv_kernel, dim3(96), dim3(256), 0, stream, Wq, Wk, Wv, Wb);
    hipLaunchKernelGGL(proj_kernel, dim3(BB * SS / 64), dim3(256), 0, stream,
                       x, Wb, q_ws, k_ws, vT_ws);
    hipLaunchKernelGGL(attn_kernel, dim3(BB * SS / 16 * 4), dim3(64), 0, stream,
                       q_ws, k_ws, vT_ws, pO32, pml);
    hipLaunchKernelGGL(combine_kernel, dim3(BB * SS / 16), dim3(64), 0, stream,
                       pO32, pml, out);
}

// Round 7
// 64.274 us; speedup vs baseline: 3.0867x; 1.5819x over previous
//
#include <hip/hip_runtime.h>
#include <hip/hip_bf16.h>
#include <stdint.h>

#define BB 4
#define SS 4096
#define EE 1024
#define DD 64

typedef __attribute__((ext_vector_type(8))) short short8;
typedef __attribute__((ext_vector_type(4))) float f32x4;

__device__ inline uint32_t cvtpk(float lo, float hi) {
    uint32_t r;
    asm("v_cvt_pk_bf16_f32 %0, %1, %2" : "=v"(r) : "v"(lo), "v"(hi));
    return r;
}
__device__ inline float bf2f_lo(uint32_t u) {
    union { uint32_t u; float f; } v; v.u = u << 16; return v.f;
}
__device__ inline float bf2f_hi(uint32_t u) {
    union { uint32_t u; float f; } v; v.u = u & 0xFFFF0000u; return v.f;
}

#define GL16(g, l) __builtin_amdgcn_global_load_lds( \
    (const __attribute__((address_space(1))) void*)(g), \
    (__attribute__((address_space(3))) void*)(l), 16, 0, 0)

// ---------- W f32 -> bf16 concat [192][1024]: rows 0-63 Wq, 64-127 Wk, 128-191 Wv ----------
__global__ __launch_bounds__(256) void wconv_kernel(
    const float* __restrict__ Wq, const float* __restrict__ Wk,
    const float* __restrict__ Wv, ushort* __restrict__ Wb)
{
    int tid = blockIdx.x * 256 + threadIdx.x;
    int sel = tid >> 13;
    int off = (tid & 8191) * 8;
    const float* src = (sel == 0) ? Wq : ((sel == 1) ? Wk : Wv);
    float4 a = *reinterpret_cast<const float4*>(src + off);
    float4 b = *reinterpret_cast<const float4*>(src + off + 4);
    uint4 o;
    o.x = cvtpk(a.x, a.y); o.y = cvtpk(a.z, a.w);
    o.z = cvtpk(b.x, b.y); o.w = cvtpk(b.z, b.w);
    *reinterpret_cast<uint4*>(Wb + (size_t)sel * 65536 + off) = o;
}

// ---------- Projection: async gload_lds pipeline, 3-deep, counted vmcnt ----------
__global__ __launch_bounds__(256) void proj_kernel(
    const float* __restrict__ x, const ushort* __restrict__ Wb,
    ushort* __restrict__ q_ws, ushort* __restrict__ k_ws, ushort* __restrict__ vT_ws)
{
    __shared__ __align__(16) char smem[3 * 20480];
    const int t = threadIdx.x;
    const int wid = t >> 6, lane = t & 63, g = lane >> 4, lr = lane & 15;
    const int m0 = blockIdx.x * 64;
    const int NT = EE / 32;   // 32 tiles

    f32x4 acc[3][4];
#pragma unroll
    for (int ni = 0; ni < 3; ++ni)
#pragma unroll
        for (int mi = 0; mi < 4; ++mi) acc[ni][mi] = (f32x4)(0.0f);

#define PSTAGE(KT, BUFI) do { \
    char* xb_ = smem + (BUFI) * 20480; \
    char* wb_ = xb_ + 8192; \
    int e0_ = (KT) * 32; \
    _Pragma("unroll") \
    for (int i = 0; i < 2; ++i) { \
        int v = i * 256 + t; int row = v >> 3, c = v & 7; \
        GL16(&x[(size_t)(m0 + row) * EE + e0_ + ((c ^ (row & 7)) << 2)], xb_ + v * 16); \
    } \
    _Pragma("unroll") \
    for (int i = 0; i < 3; ++i) { \
        int v = i * 256 + t; int row = v >> 2, u = v & 3; \
        GL16(&Wb[(size_t)row * EE + e0_ + ((u ^ (row & 3)) << 3)], wb_ + v * 16); \
    } \
} while (0)

    PSTAGE(0, 0); PSTAGE(1, 1); PSTAGE(2, 2);

    for (int kt = 0; kt < NT; ++kt) {
        asm volatile("s_waitcnt vmcnt(10)" ::: "memory");
        __builtin_amdgcn_s_barrier();
        __builtin_amdgcn_sched_barrier(0);

        const char* xb = smem + (kt % 3) * 20480;
        const char* wb = xb + 8192;

        short8 af[3], bf[4];
#pragma unroll
        for (int ni = 0; ni < 3; ++ni) {
            int row = wid * 48 + ni * 16 + lr;
            af[ni] = *reinterpret_cast<const short8*>(wb + row * 64 + ((g ^ (lr & 3)) << 4));
        }
#pragma unroll
        for (int mi = 0; mi < 4; ++mi) {
            int row = mi * 16 + lr;
            int u0 = (2 * g) ^ (lr & 7);
            f32x4 lo = *reinterpret_cast<const f32x4*>(xb + row * 128 + u0 * 16);
            f32x4 hi = *reinterpret_cast<const f32x4*>(xb + row * 128 + (u0 ^ 1) * 16);
            union { short8 s; uint32_t u[4]; } p;
            p.u[0] = cvtpk(lo[0], lo[1]); p.u[1] = cvtpk(lo[2], lo[3]);
            p.u[2] = cvtpk(hi[0], hi[1]); p.u[3] = cvtpk(hi[2], hi[3]);
            bf[mi] = p.s;
        }
#pragma unroll
        for (int ni = 0; ni < 3; ++ni)
#pragma unroll
            for (int mi = 0; mi < 4; ++mi)
                acc[ni][mi] = __builtin_amdgcn_mfma_f32_16x16x32_bf16(af[ni], bf[mi], acc[ni][mi], 0, 0, 0);

        asm volatile("s_waitcnt lgkmcnt(0)" ::: "memory");
        __builtin_amdgcn_sched_barrier(0);
        __builtin_amdgcn_s_barrier();
        __builtin_amdgcn_sched_barrier(0);

        int nx = (kt + 3 < NT) ? kt + 3 : NT - 1;
        PSTAGE(nx, kt % 3);
    }

#pragma unroll
    for (int ni = 0; ni < 3; ++ni) {
        int n0 = wid * 48 + ni * 16 + 4 * g;
        int sel = n0 >> 6, d0 = n0 & 63;
#pragma unroll
        for (int mi = 0; mi < 4; ++mi) {
            int m = m0 + mi * 16 + lr;
            int b = m >> 12, s = m & (SS - 1);
            uint2 p;
            p.x = cvtpk(acc[ni][mi][0], acc[ni][mi][1]);
            p.y = cvtpk(acc[ni][mi][2], acc[ni][mi][3]);
            if (sel == 0) {
                *reinterpret_cast<uint2*>(q_ws + ((size_t)b * SS + s) * DD + d0) = p;
            } else if (sel == 1) {
                *reinterpret_cast<uint2*>(k_ws + ((size_t)b * SS + s) * DD + d0) = p;
            } else {
                vT_ws[((size_t)b * DD + d0 + 0) * SS + s] = (ushort)(p.x & 0xFFFF);
                vT_ws[((size_t)b * DD + d0 + 1) * SS + s] = (ushort)(p.x >> 16);
                vT_ws[((size_t)b * DD + d0 + 2) * SS + s] = (ushort)(p.y & 0xFFFF);
                vT_ws[((size_t)b * DD + d0 + 3) * SS + s] = (ushort)(p.y >> 16);
            }
        }
    }
}

// ---------- Flash attention: 4-wave blocks, 64-row q-block, shared LDS K/V DMA, split-KV ----------
__global__ __launch_bounds__(256) void attn_kernel(
    const ushort* __restrict__ q_ws, const ushort* __restrict__ k_ws,
    const ushort* __restrict__ vT_ws, uint32_t* __restrict__ pO32,
    float* __restrict__ pml)
{
    __shared__ __align__(16) char kv_lds[2][16384];   // per buf: K 8KB | V^T 8KB (src-preswizzled)
    __shared__ __align__(16) char P_lds[4][2048];     // per-wave swizzled P
    const int t = threadIdx.x;
    const int wid = t >> 6, lane = t & 63, g = lane >> 4, lr = lane & 15;
    const int bid = blockIdx.x;
    const int f = bid & 3;
    const int b = (bid >> 2) & 3;
    const int qblk = 63 - (bid >> 4);     // heavy q-blocks first
    const int qb_w = qblk * 64 + wid * 16;

    const ushort* qp = q_ws + ((size_t)b * SS + qb_w + lr) * DD;
    short8 qf0 = *reinterpret_cast<const short8*>(qp + g * 8);
    short8 qf1 = *reinterpret_cast<const short8*>(qp + 32 + g * 8);

    float m_r = -1e30f, l_r = 0.0f;
    f32x4 acc[4];
#pragma unroll
    for (int i = 0; i < 4; ++i) acc[i] = (f32x4)(0.0f);

    const float sc = 0.125f * 1.44269504f;
    const int nt = qblk + 1;              // kv tiles of 64 for this q-block
    const int nfull = (qb_w + 1) >> 6;    // maskless tiles for THIS wave
    const int cs = (nt + 3) >> 2;
    const int t0 = f * cs;
    const int t1 = min(nt, (f + 1) * cs);
    const ushort* kbase = k_ws + (size_t)b * SS * DD;
    const ushort* vbase = vT_ws + (size_t)b * DD * SS;
    char* pbase = P_lds[wid];

    // stage one kv tile: K rows (128B, swizzled cols) + V^T rows (swizzled cols)
#define ASTAGE(KT, BUFI) do { \
    char* kb_ = kv_lds[BUFI]; \
    int kv0_ = (KT) * 64; \
    _Pragma("unroll") \
    for (int i = 0; i < 2; ++i) { \
        int v = i * 256 + t; int row = v >> 3, c = v & 7; \
        GL16(kbase + (size_t)(kv0_ + row) * DD + ((c ^ (row & 7)) << 3), kb_ + v * 16); \
    } \
    _Pragma("unroll") \
    for (int i = 0; i < 2; ++i) { \
        int v = i * 256 + t; int row = v >> 3, c = v & 7; \
        GL16(vbase + (size_t)row * SS + kv0_ + ((c ^ (row & 7)) << 3), kb_ + 8192 + v * 16); \
    } \
} while (0)

    if (t0 < t1) {
        ASTAGE(t0, 0);
        ASTAGE((t0 + 1 < t1) ? t0 + 1 : t0, 1);

        for (int kt = t0; kt < t1; ++kt) {
            const int cur = (kt - t0) & 1;
            asm volatile("s_waitcnt vmcnt(4)" ::: "memory");
            __builtin_amdgcn_s_barrier();
            __builtin_amdgcn_sched_barrier(0);

            const char* kb = kv_lds[cur];
            const char* vb = kb + 8192;
            const int kv0 = kt * 64;

            // S^T = K Q^T : sfr[nf][jr] = S[kv0+nf*16+4g+jr][qb_w+lr]
            f32x4 sfr[4];
#pragma unroll
            for (int nf = 0; nf < 4; ++nf) {
                int row = nf * 16 + lr;
                short8 b0 = *reinterpret_cast<const short8*>(kb + row * 128 + ((g ^ (row & 7)) << 4));
                short8 b1 = *reinterpret_cast<const short8*>(kb + row * 128 + (((4 + g) ^ (row & 7)) << 4));
                f32x4 s_ = (f32x4)(0.0f);
                s_ = __builtin_amdgcn_mfma_f32_16x16x32_bf16(b0, qf0, s_, 0, 0, 0);
                s_ = __builtin_amdgcn_mfma_f32_16x16x32_bf16(b1, qf1, s_, 0, 0, 0);
                sfr[nf] = s_;
            }
#pragma unroll
            for (int nf = 0; nf < 4; ++nf) sfr[nf] *= sc;
            if (kt >= nfull) {
#pragma unroll
                for (int nf = 0; nf < 4; ++nf)
#pragma unroll
                    for (int jr = 0; jr < 4; ++jr)
                        if (kv0 + nf * 16 + 4 * g + jr > qb_w + lr) sfr[nf][jr] = -1e30f;
            }
            float mt = fmaxf(fmaxf(fmaxf(sfr[0][0], sfr[0][1]), fmaxf(sfr[0][2], sfr[0][3])),
                             fmaxf(fmaxf(sfr[1][0], sfr[1][1]), fmaxf(sfr[1][2], sfr[1][3])));
            mt = fmaxf(mt, fmaxf(fmaxf(fmaxf(sfr[2][0], sfr[2][1]), fmaxf(sfr[2][2], sfr[2][3])),
                                 fmaxf(fmaxf(sfr[3][0], sfr[3][1]), fmaxf(sfr[3][2], sfr[3][3]))));
            mt = fmaxf(mt, __shfl_xor(mt, 16));
            mt = fmaxf(mt, __shfl_xor(mt, 32));
            float mn = fmaxf(m_r, mt);
            float sf = exp2f(m_r - mn);
            m_r = mn;
            float ps = 0.0f;
            uint32_t pk[8];
#pragma unroll
            for (int nf = 0; nf < 4; ++nf) {
                float e0_ = exp2f(sfr[nf][0] - mn);
                float e1_ = exp2f(sfr[nf][1] - mn);
                float e2_ = exp2f(sfr[nf][2] - mn);
                float e3_ = exp2f(sfr[nf][3] - mn);
                ps += (e0_ + e1_) + (e2_ + e3_);
                pk[nf * 2 + 0] = cvtpk(e0_, e1_);
                pk[nf * 2 + 1] = cvtpk(e2_, e3_);
            }
            ps += __shfl_xor(ps, 16);
            ps += __shfl_xor(ps, 32);
            l_r = l_r * sf + ps;
#pragma unroll
            for (int df = 0; df < 4; ++df) acc[df] *= sf;

            // P -> per-wave swizzled LDS: element (lr, e=nf*16+4g+jr), 16B slot ^ (lr&7)
#pragma unroll
            for (int nf = 0; nf < 4; ++nf) {
                int slot = nf * 2 + (g >> 1);
                uint2 w_; w_.x = pk[nf * 2]; w_.y = pk[nf * 2 + 1];
                *reinterpret_cast<uint2*>(pbase + lr * 128 + ((slot ^ (lr & 7)) << 4) + (g & 1) * 8) = w_;
            }
            // cross-lane LDS RAW fence (other lanes' writes consumed below)
            asm volatile("s_waitcnt lgkmcnt(0)" ::: "memory");
            __builtin_amdgcn_sched_barrier(0);

            // O^T += V^T P : A = V^T rows, B = P (col=q=lr, k=kv)
#pragma unroll
            for (int c = 0; c < 2; ++c) {
                short8 pb_ = *reinterpret_cast<const short8*>(pbase + lr * 128 + (((c * 4 + g) ^ (lr & 7)) << 4));
#pragma unroll
                for (int df = 0; df < 4; ++df) {
                    int row = df * 16 + lr;
                    short8 vb_ = *reinterpret_cast<const short8*>(vb + row * 128 + (((c * 4 + g) ^ (row & 7)) << 4));
                    acc[df] = __builtin_amdgcn_mfma_f32_16x16x32_bf16(vb_, pb_, acc[df], 0, 0, 0);
                }
            }

            // all LDS reads from this buffer done before DMA overwrites it
            asm volatile("s_waitcnt lgkmcnt(0)" ::: "memory");
            __builtin_amdgcn_sched_barrier(0);
            __builtin_amdgcn_s_barrier();
            __builtin_amdgcn_sched_barrier(0);

            int nx = (kt + 2 < t1) ? kt + 2 : t1 - 1;   // clamped dummy keeps vmcnt uniform
            ASTAGE(nx, cur);
        }
    }

    // store partial: O^T bf16-packed along d: [32 dpairs][16 q], plus m,l
    const int pidx = ((b * 256 + qblk * 4 + wid) * 4 + f);
    uint32_t* po = pO32 + (size_t)pidx * 512;
#pragma unroll
    for (int df = 0; df < 4; ++df) {
        po[(df * 8 + 2 * g + 0) * 16 + lr] = cvtpk(acc[df][0], acc[df][1]);
        po[(df * 8 + 2 * g + 1) * 16 + lr] = cvtpk(acc[df][2], acc[df][3]);
    }
    if (g == 0) {
        pml[(size_t)pidx * 32 + lr] = m_r;
        pml[(size_t)pidx * 32 + 16 + lr] = l_r;
    }
}

// ---------- Combine partials ----------
__global__ __launch_bounds__(64) void combine_kernel(
    const uint32_t* __restrict__ pO32, const float* __restrict__ pml,
    float* __restrict__ out)
{
    const int t = threadIdx.x;
    const int q = t & 15, dblk = t >> 4;
    const int grp = blockIdx.x;          // b*256 + qt16
    const int b = grp >> 8, qt = grp & 255;
    const int qb = qt * 16;

    float mf[4], lf[4];
#pragma unroll
    for (int f = 0; f < 4; ++f) {
        mf[f] = pml[(size_t)(grp * 4 + f) * 32 + q];
        lf[f] = pml[(size_t)(grp * 4 + f) * 32 + 16 + q];
    }
    float m = fmaxf(fmaxf(mf[0], mf[1]), fmaxf(mf[2], mf[3]));
    float w[4], l = 0.0f;
#pragma unroll
    for (int f = 0; f < 4; ++f) { w[f] = exp2f(mf[f] - m); l += w[f] * lf[f]; }

    float o[16];
#pragma unroll
    for (int i = 0; i < 16; ++i) o[i] = 0.0f;
#pragma unroll
    for (int f = 0; f < 4; ++f) {
        if (w[f] == 0.0f) continue;
        const uint32_t* src = pO32 + (size_t)(grp * 4 + f) * 512 + dblk * 128 + q;
#pragma unroll
        for (int r0 = 0; r0 < 8; ++r0) {
            uint32_t u = src[r0 * 16];
            o[2 * r0 + 0] += w[f] * bf2f_lo(u);
            o[2 * r0 + 1] += w[f] * bf2f_hi(u);
        }
    }
    float inv = 1.0f / l;
    float* op = out + ((size_t)b * SS + qb + q) * DD + dblk * 16;
#pragma unroll
    for (int i = 0; i < 4; ++i) {
        float4 st;
        st.x = o[4 * i + 0] * inv; st.y = o[4 * i + 1] * inv;
        st.z = o[4 * i + 2] * inv; st.w = o[4 * i + 3] * inv;
        *reinterpret_cast<float4*>(op + 4 * i) = st;
    }
}

extern "C" void kernel_launch(void* const* d_in, const int* in_sizes, int n_in,
                              void* d_out, int out_size, void* d_ws, size_t ws_size,
                              hipStream_t stream) {
    const float* x  = (const float*)d_in[0];
    const float* Wk = (const float*)d_in[1];
    const float* Wq = (const float*)d_in[2];
    const float* Wv = (const float*)d_in[3];
    ushort* q_ws  = (ushort*)d_ws;
    ushort* k_ws  = q_ws + (size_t)BB * SS * DD;
    ushort* vT_ws = k_ws + (size_t)BB * SS * DD;
    ushort* Wb    = vT_ws + (size_t)BB * SS * DD;
    uint32_t* pO32 = (uint32_t*)(Wb + 192 * 1024);          // 4096 * 512 u32 = 8 MB
    float* pml     = (float*)(pO32 + (size_t)4096 * 512);   // 4096 * 32 f32 = 512 KB
    float* out = (float*)d_out;

    hipLaunchKernelGGL(wconv_kernel, dim3(96), dim3(256), 0, stream, Wq, Wk, Wv, Wb);
    hipLaunchKernelGGL(proj_kernel, dim3(BB * SS / 64), dim3(256), 0, stream,
                       x, Wb, q_ws, k_ws, vT_ws);
    hipLaunchKernelGGL(attn_kernel, dim3(BB * 64 * 4 / 4 * 4), dim3(256), 0, stream,
                       q_ws, k_ws, vT_ws, pO32, pml);
    hipLaunchKernelGGL(combine_kernel, dim3(BB * SS / 16), dim3(64), 0, stream,
                       pO32, pml, out);
}